// Round 8
// baseline (500.927 us; speedup 1.0000x reference)
//
#include <hip/hip_runtime.h>

#define CELLS 81
#define ND 9
#define HID 100
#define HALF 50

// d_ws float layout:
//   W1R: [d][j][8], j = global unit-pair 0..49: {A0,B0,C0,A1,B1,C1,pad,pad}
//        A_u = W1[u*27+d], B_u = W1[u*27+9+d], C_u = W1[u*27+18+d]
//   W2R: [j][24]: u0 digits 0..8 at +0, u1 digits 0..8 at +12 (pads zeroed)
#define W1R_OFF 0
#define W2R_OFF (9 * 50 * 8)   // 3600
#define WS_FLOATS (W2R_OFF + 50 * 24)

__global__ __launch_bounds__(64) void prep_kernel(
    const float* __restrict__ W1, const float* __restrict__ W2,
    float* __restrict__ ws)
{
    int t = threadIdx.x;
    for (int i = t; i < 9 * 50; i += 64) {
        int d = i / 50, j = i - d * 50;
        int u0 = 2 * j, u1 = 2 * j + 1;
        float* r = ws + W1R_OFF + (size_t)i * 8;
        r[0] = W1[u0 * 27 + d];
        r[1] = W1[u0 * 27 + 9 + d];
        r[2] = W1[u0 * 27 + 18 + d];
        r[3] = W1[u1 * 27 + d];
        r[4] = W1[u1 * 27 + 9 + d];
        r[5] = W1[u1 * 27 + 18 + d];
        r[6] = 0.f; r[7] = 0.f;
    }
    for (int j = t; j < 50; j += 64) {
        int u0 = 2 * j, u1 = 2 * j + 1;
        float* r = ws + W2R_OFF + (size_t)j * 24;
        #pragma unroll
        for (int d = 0; d < ND; ++d) {
            r[d]      = W2[d * HID + u0];
            r[12 + d] = W2[d * HID + u1];
        }
        r[9] = r[10] = r[11] = r[21] = r[22] = r[23] = 0.f;
    }
}

__global__ __launch_bounds__(128) void sudoku_kernel(
    const float* __restrict__ x_all,
    const float* __restrict__ W1,
    const float* __restrict__ ws,
    float* __restrict__ out,
    int nBoards)
{
    const int board = blockIdx.x;
    const int tid = threadIdx.x;      // two waves per board
    const int w   = tid >> 6;         // wave owns units [w*50, w*50+50)
    const int lw  = tid & 63;         // lane = empty-cell slot
    const int ubase = w * HALF;
    const int jbase = ubase >> 1;     // global unit-pair base

    const float* x = x_all + (size_t)board * (CELLS * ND);
    float* po = out + (size_t)board * (CELLS * ND);
    float* fo = out + (size_t)nBoards * (CELLS * ND) + (size_t)board * (CELLS * ND);

    __shared__ __align__(16) float parts[2][2][64][12];   // 24576 B dbuf partials
    __shared__ float cnt[3 * 81];
    __shared__ int   digit[CELLS];
    __shared__ unsigned long long em_sh[2];

    // ---- init: zero counts, copy x -> po ----
    for (int i = tid; i < 243; i += 128) cnt[i] = 0.f;
    for (int i = tid; i < CELLS * ND; i += 128) po[i] = x[i];
    __syncthreads();

    // ---- digits, counts, per-wave emptiness ballots ----
    bool isEmpty = false;
    if (tid < CELLS) {
        int q = tid, dig = -1;
        #pragma unroll
        for (int d = 0; d < ND; ++d) if (dig < 0 && x[q*ND+d] > 0.5f) dig = d;
        digit[q] = dig;
        if (dig >= 0) {
            int r = q/9, c = q%9, b = (r/3)*3 + c/3;
            atomicAdd(&cnt[r*9+dig], 1.f);
            atomicAdd(&cnt[81+c*9+dig], 1.f);
            atomicAdd(&cnt[162+b*9+dig], 1.f);
        } else isEmpty = true;
    }
    unsigned long long mk = __ballot(isEmpty);
    if (lw == 0) em_sh[w] = mk;
    __syncthreads();

    const unsigned long long em0 = em_sh[0], em1 = em_sh[1];
    const int c0  = __popcll(em0);
    const int ne0 = c0 + __popcll(em1);

    // lane lw -> rank-lw empty cell (sentinel 127); identical in both waves
    int myq = 127;
    if (lw < ne0) {
        int rank = lw; unsigned long long mm = em0; int base = 0;
        if (rank >= c0) { rank -= c0; mm = em1; base = 64; }
        for (int b = 0; b < 64; ++b)
            if ((mm >> b) & 1ull) { if (rank == 0) { myq = base + b; break; } --rank; }
    }
    const int myr = (myq < 81) ? myq / 9 : 0;
    const int myc = (myq < 81) ? myq % 9 : 0;
    const int myb = (myr / 3) * 3 + myc / 3;

    // ---- z init: lane's 27 counts in regs; W1 rows via uniform s_load ----
    float crr[9], ccc[9], cbb[9];
    #pragma unroll
    for (int j = 0; j < 9; ++j) {
        crr[j] = cnt[myr*9+j];
        ccc[j] = cnt[81+myc*9+j];
        cbb[j] = cnt[162+myb*9+j];
    }
    float z[HALF];
    #pragma unroll
    for (int u = 0; u < HALF; ++u) {
        const float* wr = W1 + (size_t)(ubase + u) * 27;   // uniform
        float a = 0.f;
        #pragma unroll
        for (int j = 0; j < 9; ++j)
            a += crr[j]*wr[j] + ccc[j]*wr[9+j] + cbb[j]*wr[18+j];
        z[u] = a;
    }

    bool active = (lw < ne0);
    float b0 = 0.f, b1 = 0.f, b2 = 0.f;
    int dc = 0;

    // ---- solve loop: 1 barrier/iter; weights via SMEM, not DS ----
    for (int it = 0; it < ne0; ++it) {
        const int dcs = __builtin_amdgcn_readfirstlane(dc);
        const float* w1r = ws + W1R_OFF + (size_t)(dcs * 50 + jbase) * 8;
        const float* w2r = ws + W2R_OFF + (size_t)jbase * 24;

        float acc[ND];
        #pragma unroll
        for (int d = 0; d < ND; ++d) acc[d] = 0.f;

        // fused z-update + relu + partial logits; all weight reads uniform
        #pragma unroll
        for (int j = 0; j < 25; ++j) {
            float A0 = w1r[j*8+0], B0 = w1r[j*8+1], C0 = w1r[j*8+2];
            float A1 = w1r[j*8+3], B1 = w1r[j*8+4], C1 = w1r[j*8+5];
            float z0 = fmaf(b0, A0, fmaf(b1, B0, fmaf(b2, C0, z[2*j])));
            float z1 = fmaf(b0, A1, fmaf(b1, B1, fmaf(b2, C1, z[2*j+1])));
            z[2*j] = z0; z[2*j+1] = z1;
            float h0 = fmaxf(z0, 0.f), h1 = fmaxf(z1, 0.f);
            #pragma unroll
            for (int d = 0; d < ND; ++d) acc[d] = fmaf(h0, w2r[j*24+d], acc[d]);
            #pragma unroll
            for (int d = 0; d < ND; ++d) acc[d] = fmaf(h1, w2r[j*24+12+d], acc[d]);
        }

        // publish partial, combine with other wave's half (dbuf, 1 barrier)
        const int buf = it & 1;
        float* pp = &parts[buf][w][lw][0];
        *(float4*)(pp)     = make_float4(acc[0], acc[1], acc[2], acc[3]);
        *(float4*)(pp + 4) = make_float4(acc[4], acc[5], acc[6], acc[7]);
        pp[8] = acc[8];
        __syncthreads();
        const float* op = &parts[buf][1 - w][lw][0];
        float4 oa = *(const float4*)(op);
        float4 ob = *(const float4*)(op + 4);
        acc[0] += oa.x; acc[1] += oa.y; acc[2] += oa.z; acc[3] += oa.w;
        acc[4] += ob.x; acc[5] += ob.y; acc[6] += ob.z; acc[7] += ob.w;
        acc[8] += op[8];   // own+other: commutative -> identical in both waves

        // softmax + per-cell best digit (strict >: first max)
        float m9 = acc[0];
        #pragma unroll
        for (int d = 1; d < ND; ++d) m9 = fmaxf(m9, acc[d]);
        float s = 0.f;
        #pragma unroll
        for (int d = 0; d < ND; ++d) { acc[d] = expf(acc[d] - m9); s += acc[d]; }
        float inv = 1.f / s;
        float bv = -1.f; int bd = 0;
        #pragma unroll
        for (int d = 0; d < ND; ++d) {
            acc[d] *= inv;
            if (acc[d] > bv) { bv = acc[d]; bd = d; }
        }

        // global argmax: packed key -> max value, tie -> smallest q
        unsigned long long key = 0ull;
        if (active)
            key = ((unsigned long long)__float_as_uint(bv) << 32)
                | (unsigned)(((127 - myq) << 4) | bd);
        #pragma unroll
        for (int off = 32; off >= 1; off >>= 1) {
            unsigned long long o = __shfl_xor(key, off);
            if (o > key) key = o;
        }
        const int qw = 127 - ((int)(key >> 4) & 0x7F);
        const int dw = (int)(key & 0xFull);

        // winner retires: wave 0's copy writes po (final softmax) + digit
        if (active && myq == qw) {
            if (w == 0) {
                #pragma unroll
                for (int d = 0; d < ND; ++d) po[myq*ND + d] = acc[d];
                digit[myq] = dw;
            }
            active = false;
        }
        const int pr = qw/9, pcc = qw%9, pb = (pr/3)*3 + pcc/3;
        b0 = (myr == pr)  ? 1.f : 0.f;
        b1 = (myc == pcc) ? 1.f : 0.f;
        b2 = (myb == pb)  ? 1.f : 0.f;
        dc = dw;
    }

    // ---- x_final ----
    __syncthreads();
    for (int i = tid; i < CELLS * ND; i += 128) {
        int q = i / ND, d = i - q * ND;
        fo[i] = (digit[q] == d) ? 1.f : 0.f;
    }
}

extern "C" void kernel_launch(void* const* d_in, const int* in_sizes, int n_in,
                              void* d_out, int out_size, void* d_ws, size_t ws_size,
                              hipStream_t stream) {
    const float* x  = (const float*)d_in[0];
    // d_in[1] is the constraint mask c — structurally known, not needed.
    const float* W1 = (const float*)d_in[2];
    const float* W2 = (const float*)d_in[3];
    float* out = (float*)d_out;
    float* ws  = (float*)d_ws;
    int nBoards = in_sizes[0] / (CELLS * ND);
    prep_kernel<<<1, 64, 0, stream>>>(W1, W2, ws);
    sudoku_kernel<<<nBoards, 128, 0, stream>>>(x, W1, ws, out, nBoards);
}

// Round 9
// 153.477 us; speedup vs baseline: 3.2639x; 3.2639x over previous
//
#include <hip/hip_runtime.h>

#define CELLS 81
#define ND 9
#define HID 100

typedef float v2f __attribute__((ext_vector_type(2)));

#define W1P_SZ (9 * 50 * 8)   // 3600 floats: [d][pair]{A0,A1,B0,B1,C0,C1,0,0}
#define W2P_SZ (50 * 20)      // 1000 floats: [pair]{d0u0,d0u1,...,d8u0,d8u1,0,0}

__global__ __launch_bounds__(64) void prep_kernel(
    const float* __restrict__ W1, const float* __restrict__ W2,
    float* __restrict__ ws)
{
    const int t = threadIdx.x;
    for (int i = t; i < 9 * 50; i += 64) {
        int d = i / 50, j = i - d * 50;
        int u0 = 2 * j, u1 = u0 + 1;
        float* r = ws + (size_t)i * 8;
        r[0] = W1[u0*27 + d];      r[1] = W1[u1*27 + d];
        r[2] = W1[u0*27 + 9 + d];  r[3] = W1[u1*27 + 9 + d];
        r[4] = W1[u0*27 + 18 + d]; r[5] = W1[u1*27 + 18 + d];
        r[6] = 0.f; r[7] = 0.f;
    }
    for (int j = t; j < 50; j += 64) {
        int u0 = 2 * j, u1 = u0 + 1;
        float* r = ws + W1P_SZ + (size_t)j * 20;
        #pragma unroll
        for (int d = 0; d < ND; ++d) {
            r[2*d]     = W2[d*HID + u0];
            r[2*d + 1] = W2[d*HID + u1];
        }
        r[18] = 0.f; r[19] = 0.f;
    }
}

__global__ __launch_bounds__(128) void sudoku_kernel(
    const float* __restrict__ x_all,
    const float* __restrict__ ws,
    float* __restrict__ out,
    int nBoards)
{
    const int board = blockIdx.x;
    const int tid = threadIdx.x;      // two waves per board
    const int w   = tid >> 6;         // wave owns unit-pairs [w*25, w*25+25)
    const int lw  = tid & 63;         // lane = empty-cell slot (rank order = q order)
    const int jbase = w * 25;

    const float* x = x_all + (size_t)board * (CELLS * ND);
    float* po = out + (size_t)board * (CELLS * ND);
    float* fo = out + (size_t)nBoards * (CELLS * ND) + (size_t)board * (CELLS * ND);

    __shared__ __align__(16) float w1s[W1P_SZ];            // 14400 B
    __shared__ __align__(16) float w2s[W2P_SZ];            // 4000 B
    __shared__ __align__(16) float parts[2][2][64][12];    // 12288 B dbuf
    __shared__ float cnt[3 * 81];
    __shared__ int   digit[CELLS];
    __shared__ unsigned long long em_sh[2];

    // ---- stage packed weights ws -> LDS (coalesced), init cnt, copy x -> po ----
    for (int i = tid; i < W1P_SZ / 4; i += 128)
        ((float4*)w1s)[i] = ((const float4*)ws)[i];
    for (int i = tid; i < W2P_SZ / 4; i += 128)
        ((float4*)w2s)[i] = ((const float4*)(ws + W1P_SZ))[i];
    for (int i = tid; i < 243; i += 128) cnt[i] = 0.f;
    for (int i = tid; i < CELLS * ND; i += 128) po[i] = x[i];
    __syncthreads();

    // ---- digits, counts, per-wave emptiness ballots ----
    bool isEmpty = false;
    if (tid < CELLS) {
        int q = tid, dig = -1;
        #pragma unroll
        for (int d = 0; d < ND; ++d) if (dig < 0 && x[q*ND+d] > 0.5f) dig = d;
        digit[q] = dig;
        if (dig >= 0) {
            int r = q/9, c = q%9, b = (r/3)*3 + c/3;
            atomicAdd(&cnt[r*9+dig], 1.f);
            atomicAdd(&cnt[81+c*9+dig], 1.f);
            atomicAdd(&cnt[162+b*9+dig], 1.f);
        } else isEmpty = true;
    }
    unsigned long long mk = __ballot(isEmpty);
    if (lw == 0) em_sh[w] = mk;
    __syncthreads();

    const unsigned long long em0 = em_sh[0], em1 = em_sh[1];
    const int c0  = __popcll(em0);
    const int ne0 = c0 + __popcll(em1);

    // lane lw -> rank-lw empty cell (ascending q; sentinel 127)
    int myq = 127;
    if (lw < ne0) {
        int rank = lw; unsigned long long mm = em0; int base = 0;
        if (rank >= c0) { rank -= c0; mm = em1; base = 64; }
        for (int b = 0; b < 64; ++b)
            if ((mm >> b) & 1ull) { if (rank == 0) { myq = base + b; break; } --rank; }
    }
    const int myr = (myq < 81) ? myq / 9 : 0;
    const int myc = (myq < 81) ? myq % 9 : 0;
    const int myb = (myr / 3) * 3 + myc / 3;

    // ---- z init: 27 counts in regs, accumulate over packed W1 per digit ----
    float crr[9], ccc[9], cbb[9];
    #pragma unroll
    for (int j = 0; j < 9; ++j) {
        crr[j] = cnt[myr*9+j];
        ccc[j] = cnt[81+myc*9+j];
        cbb[j] = cnt[162+myb*9+j];
    }
    v2f z2[25];
    #pragma unroll
    for (int j = 0; j < 25; ++j) {
        v2f a = (v2f){0.f, 0.f};
        #pragma unroll
        for (int d = 0; d < 9; ++d) {
            const float* p = &w1s[(d*50 + jbase + j) * 8];
            float4 ab = *(const float4*)p;         // A0 A1 B0 B1
            v2f Cv = *(const v2f*)(p + 4);         // C0 C1
            v2f Av = (v2f){ab.x, ab.y}, Bv = (v2f){ab.z, ab.w};
            a += crr[d]*Av + ccc[d]*Bv + cbb[d]*Cv;
        }
        z2[j] = a;
    }

    bool active = (lw < ne0);
    v2f b0v = (v2f){0.f,0.f}, b1v = (v2f){0.f,0.f}, b2v = (v2f){0.f,0.f};
    int dc = 0;
    float pfin[ND];                      // winner's final softmax (reg-held)

    // ---- solve loop: 1 barrier/iter, zero global stores inside ----
    for (int it = 0; it < ne0; ++it) {
        const int dcs = __builtin_amdgcn_readfirstlane(dc);
        const float* w1r = &w1s[(dcs*50 + jbase) * 8];
        const float* w2r = &w2s[jbase * 20];

        v2f acc2[ND];
        #pragma unroll
        for (int d = 0; d < ND; ++d) acc2[d] = (v2f){0.f, 0.f};

        // fused z-update + relu + packed partial logits over own 25 pairs
        #pragma unroll
        for (int j = 0; j < 25; ++j) {
            const float* p = w1r + j*8;
            float4 ab = *(const float4*)p;
            v2f Cv = *(const v2f*)(p + 4);
            v2f Av = (v2f){ab.x, ab.y}, Bv = (v2f){ab.z, ab.w};
            v2f zv = z2[j];
            zv = b0v*Av + (b1v*Bv + (b2v*Cv + zv));   // pk fma chain
            z2[j] = zv;
            v2f h;
            h.x = fmaxf(zv.x, 0.f);
            h.y = fmaxf(zv.y, 0.f);
            const float* q = w2r + j*20;
            float4 w01 = *(const float4*)q;
            float4 w23 = *(const float4*)(q + 4);
            float4 w45 = *(const float4*)(q + 8);
            float4 w67 = *(const float4*)(q + 12);
            v2f w8 = *(const v2f*)(q + 16);
            acc2[0] += h * (v2f){w01.x, w01.y};
            acc2[1] += h * (v2f){w01.z, w01.w};
            acc2[2] += h * (v2f){w23.x, w23.y};
            acc2[3] += h * (v2f){w23.z, w23.w};
            acc2[4] += h * (v2f){w45.x, w45.y};
            acc2[5] += h * (v2f){w45.z, w45.w};
            acc2[6] += h * (v2f){w67.x, w67.y};
            acc2[7] += h * (v2f){w67.z, w67.w};
            acc2[8] += h * w8;
        }

        float acc[ND];
        #pragma unroll
        for (int d = 0; d < ND; ++d) acc[d] = acc2[d].x + acc2[d].y;

        // exchange halves (dbuf, single barrier); own+other commutative-exact
        const int buf = it & 1;
        float* pp = &parts[buf][w][lw][0];
        *(float4*)(pp)     = make_float4(acc[0], acc[1], acc[2], acc[3]);
        *(float4*)(pp + 4) = make_float4(acc[4], acc[5], acc[6], acc[7]);
        pp[8] = acc[8];
        __syncthreads();
        const float* op = &parts[buf][1 - w][lw][0];
        float4 oa = *(const float4*)(op);
        float4 ob = *(const float4*)(op + 4);
        acc[0] += oa.x; acc[1] += oa.y; acc[2] += oa.z; acc[3] += oa.w;
        acc[4] += ob.x; acc[5] += ob.y; acc[6] += ob.z; acc[7] += ob.w;
        acc[8] += op[8];

        // softmax + per-cell best digit (strict >: first max)
        float m9 = fmaxf(fmaxf(fmaxf(acc[0],acc[1]), fmaxf(acc[2],acc[3])),
                         fmaxf(fmaxf(acc[4],acc[5]), fmaxf(acc[6],acc[7])));
        m9 = fmaxf(m9, acc[8]);
        float s = 0.f;
        #pragma unroll
        for (int d = 0; d < ND; ++d) { acc[d] = __expf(acc[d] - m9); s += acc[d]; }
        float inv = 1.f / s;
        float bv = -1.f; int bd = 0;
        #pragma unroll
        for (int d = 0; d < ND; ++d) {
            acc[d] *= inv;
            if (acc[d] > bv) { bv = acc[d]; bd = d; }
        }

        // winner: 32-bit max butterfly, then ballot (lane order == q order)
        float bvv = active ? bv : -1.f;
        float vmax = bvv;
        #pragma unroll
        for (int off = 32; off >= 1; off >>= 1)
            vmax = fmaxf(vmax, __shfl_xor(vmax, off));
        unsigned long long msk = __ballot(bvv == vmax);
        int wl = __ffsll(msk) - 1;          // lowest lane = lowest q (first occurrence)
        int qw = __shfl(myq, wl);
        int dw = __shfl(bd, wl);

        if (active && myq == qw) {
            #pragma unroll
            for (int d = 0; d < ND; ++d) pfin[d] = acc[d];
            if (w == 0) digit[myq] = dw;    // LDS only; po written after loop
            active = false;
        }
        const int pr = qw/9, pcc = qw%9, pb = (pr/3)*3 + pcc/3;
        b0v = (v2f)((myr == pr)  ? 1.f : 0.f);
        b1v = (v2f)((myc == pcc) ? 1.f : 0.f);
        b2v = (v2f)((myb == pb)  ? 1.f : 0.f);
        dc = dw;
    }

    // ---- outputs ----
    __syncthreads();                      // digit[] visible to both waves
    if (w == 0 && lw < ne0 && myq < 81) { // each retired lane writes its final softmax
        #pragma unroll
        for (int d = 0; d < ND; ++d) po[myq*ND + d] = pfin[d];
    }
    for (int i = tid; i < CELLS * ND; i += 128) {
        int q = i / ND, d = i - q * ND;
        fo[i] = (digit[q] == d) ? 1.f : 0.f;
    }
}

extern "C" void kernel_launch(void* const* d_in, const int* in_sizes, int n_in,
                              void* d_out, int out_size, void* d_ws, size_t ws_size,
                              hipStream_t stream) {
    const float* x  = (const float*)d_in[0];
    // d_in[1] is the constraint mask c — structurally known, not needed.
    const float* W1 = (const float*)d_in[2];
    const float* W2 = (const float*)d_in[3];
    float* out = (float*)d_out;
    float* ws  = (float*)d_ws;
    int nBoards = in_sizes[0] / (CELLS * ND);
    prep_kernel<<<1, 64, 0, stream>>>(W1, W2, ws);
    sudoku_kernel<<<nBoards, 128, 0, stream>>>(x, ws, out, nBoards);
}